// Round 1
// baseline (1364.939 us; speedup 1.0000x reference)
//
#include <hip/hip_runtime.h>
#include <hip/hip_bf16.h>

#define M_TOT 16384
#define N_TOT 4096
#define K_TOT 4096

typedef __attribute__((ext_vector_type(8))) short bf16x8;
typedef __attribute__((ext_vector_type(4))) float f32x4;

__device__ inline unsigned short f2bf(float f) {
    union { float f; unsigned u; } v; v.f = f;
    unsigned u = v.u;
    u += 0x7FFFu + ((u >> 16) & 1u);   // RNE
    return (unsigned short)(u >> 16);
}

__device__ inline unsigned short sgn_bf(float f) {
    union { float f; unsigned u; } v; v.f = f;
    // bf16 +-1.0 : sign | 0x3F80
    return (unsigned short)(((v.u >> 16) & 0x8000u) | 0x3F80u);
}

// ---------------------------------------------------------------------------
// Kernel 1: per-row scale = mean(|W|), optional binarize W -> bf16 +-1
// one block per output row (4096 rows), 256 threads
// ---------------------------------------------------------------------------
__global__ void prep_weight(const float* __restrict__ w,
                            unsigned short* __restrict__ bw,  // may be null
                            float* __restrict__ scale) {
    const int row = blockIdx.x;
    const int tid = threadIdx.x;
    const float4* wr = (const float4*)(w + (size_t)row * K_TOT);
    float s = 0.f;
#pragma unroll
    for (int i = 0; i < 4; ++i) {
        int idx = tid + i * 256;            // float4 index 0..1023
        float4 v = wr[idx];
        s += fabsf(v.x) + fabsf(v.y) + fabsf(v.z) + fabsf(v.w);
        if (bw) {
            ushort4 b;
            b.x = sgn_bf(v.x); b.y = sgn_bf(v.y);
            b.z = sgn_bf(v.z); b.w = sgn_bf(v.w);
            *(ushort4*)(bw + (size_t)row * K_TOT + idx * 4) = b;
        }
    }
#pragma unroll
    for (int off = 32; off > 0; off >>= 1) s += __shfl_down(s, off, 64);
    __shared__ float red[4];
    if ((tid & 63) == 0) red[tid >> 6] = s;
    __syncthreads();
    if (tid == 0) scale[row] = (red[0] + red[1] + red[2] + red[3]) * (1.f / (float)K_TOT);
}

// ---------------------------------------------------------------------------
// Kernel 2: x fp32 -> bf16
// ---------------------------------------------------------------------------
__global__ void conv_x(const float* __restrict__ x, unsigned short* __restrict__ xb) {
    const long n4 = (long)M_TOT * K_TOT / 4;
    long i = (long)blockIdx.x * blockDim.x + threadIdx.x;
    const long stride = (long)gridDim.x * blockDim.x;
    for (; i < n4; i += stride) {
        float4 v = ((const float4*)x)[i];
        ushort4 b;
        b.x = f2bf(v.x); b.y = f2bf(v.y); b.z = f2bf(v.z); b.w = f2bf(v.w);
        ((ushort4*)xb)[i] = b;
    }
}

// ---------------------------------------------------------------------------
// Kernel 3: GEMM  out[m][n] = (A[m][:] . signW[n][:]) * scale[n] + bias[n]
// 128x128 block tile, BK=32, 256 threads = 4 waves, each wave 64x64 (4x4 MFMA tiles)
// PRECONV=true : Ap = bf16 x, Bp = bf16 +-1 weights (from ws)
// PRECONV=false: Ap = fp32 x, Bp = fp32 weights (convert inline; ws too small)
// ---------------------------------------------------------------------------
template <bool PRECONV>
__global__ __launch_bounds__(256) void gemm_bin(const void* __restrict__ Ap,
                                                const void* __restrict__ Bp,
                                                const float* __restrict__ scale,
                                                const float* __restrict__ bias,
                                                float* __restrict__ out) {
    // stride 40 elems (80B): lanes 0..15 land on 8 distinct 4-bank groups, 2-way
    // aliasing only (free per m136); 80B keeps 16B alignment for b128 reads.
    __shared__ unsigned short As[128][40];
    __shared__ unsigned short Bs[128][40];

    const int tid  = threadIdx.x;
    const int wave = tid >> 6;
    const int lane = tid & 63;
    const int quad = lane >> 4;
    const int l16  = lane & 15;
    const int wr   = wave >> 1;   // wave row (0..1)
    const int wc   = wave & 1;    // wave col (0..1)
    const int bn   = blockIdx.x * 128;
    const int bm   = blockIdx.y * 128;

    f32x4 acc[4][4] = {};

    for (int kt = 0; kt < K_TOT; kt += 32) {
        if constexpr (PRECONV) {
            const unsigned short* A = (const unsigned short*)Ap;
            const unsigned short* B = (const unsigned short*)Bp;
            const int row0 = tid >> 2;          // 0..63
            const int c8   = (tid & 3) * 8;     // 0,8,16,24
#pragma unroll
            for (int p = 0; p < 2; ++p) {
                int row = row0 + p * 64;
                int4 v = *(const int4*)(A + (size_t)(bm + row) * K_TOT + kt + c8);
                *(int4*)&As[row][c8] = v;
            }
#pragma unroll
            for (int p = 0; p < 2; ++p) {
                int row = row0 + p * 64;
                int4 v = *(const int4*)(B + (size_t)(bn + row) * K_TOT + kt + c8);
                *(int4*)&Bs[row][c8] = v;
            }
        } else {
            const float* A  = (const float*)Ap;
            const float* Bf = (const float*)Bp;
            const int row0 = tid >> 3;          // 0..31
            const int c4   = (tid & 7) * 4;     // 0..28
#pragma unroll
            for (int p = 0; p < 4; ++p) {
                int row = row0 + p * 32;
                float4 v = *(const float4*)(A + (size_t)(bm + row) * K_TOT + kt + c4);
                ushort4 b;
                b.x = f2bf(v.x); b.y = f2bf(v.y); b.z = f2bf(v.z); b.w = f2bf(v.w);
                *(ushort4*)&As[row][c4] = b;
            }
#pragma unroll
            for (int p = 0; p < 4; ++p) {
                int row = row0 + p * 32;
                float4 v = *(const float4*)(Bf + (size_t)(bn + row) * K_TOT + kt + c4);
                ushort4 b;
                b.x = sgn_bf(v.x); b.y = sgn_bf(v.y); b.z = sgn_bf(v.z); b.w = sgn_bf(v.w);
                *(ushort4*)&Bs[row][c4] = b;
            }
        }
        __syncthreads();

        // A frag: A[m = l16][k = quad*8 + e];  B frag: W[n = l16][k = quad*8 + e]
        bf16x8 af[4], bfr[4];
#pragma unroll
        for (int i = 0; i < 4; ++i)
            af[i] = *(const bf16x8*)&As[wr * 64 + i * 16 + l16][quad * 8];
#pragma unroll
        for (int j = 0; j < 4; ++j)
            bfr[j] = *(const bf16x8*)&Bs[wc * 64 + j * 16 + l16][quad * 8];
#pragma unroll
        for (int i = 0; i < 4; ++i)
#pragma unroll
            for (int j = 0; j < 4; ++j)
                acc[i][j] = __builtin_amdgcn_mfma_f32_16x16x32_bf16(af[i], bfr[j], acc[i][j], 0, 0, 0);
        __syncthreads();
    }

    // epilogue: C/D layout col = l16, row = quad*4 + reg (verified m89/m91)
#pragma unroll
    for (int j = 0; j < 4; ++j) {
        const int gn = bn + wc * 64 + j * 16 + l16;
        const float sc = scale[gn];
        const float bi = bias[gn];
#pragma unroll
        for (int i = 0; i < 4; ++i) {
            const int gm0 = bm + wr * 64 + i * 16 + quad * 4;
#pragma unroll
            for (int r = 0; r < 4; ++r)
                out[(size_t)(gm0 + r) * N_TOT + gn] = acc[i][j][r] * sc + bi;
        }
    }
}

// ---------------------------------------------------------------------------
extern "C" void kernel_launch(void* const* d_in, const int* in_sizes, int n_in,
                              void* d_out, int out_size, void* d_ws, size_t ws_size,
                              hipStream_t stream) {
    const float* x    = (const float*)d_in[0];
    const float* w    = (const float*)d_in[1];
    const float* bias = (const float*)d_in[2];
    float* out        = (float*)d_out;

    // ws layout: [scale 16KB][bw 32MB][xb 128MB]
    const size_t off_scale = 0;
    const size_t off_bw    = 16384;
    const size_t off_xb    = off_bw + (size_t)N_TOT * K_TOT * 2;
    const size_t need_full = off_xb + (size_t)M_TOT * K_TOT * 2;

    float* scale = (float*)((char*)d_ws + off_scale);
    const bool full = ws_size >= need_full;

    dim3 grid(N_TOT / 128, M_TOT / 128);

    if (full) {
        unsigned short* bw = (unsigned short*)((char*)d_ws + off_bw);
        unsigned short* xb = (unsigned short*)((char*)d_ws + off_xb);
        prep_weight<<<N_TOT, 256, 0, stream>>>(w, bw, scale);
        conv_x<<<8192, 256, 0, stream>>>(x, xb);
        gemm_bin<true><<<grid, 256, 0, stream>>>(xb, bw, scale, bias, out);
    } else {
        prep_weight<<<N_TOT, 256, 0, stream>>>(w, nullptr, scale);
        gemm_bin<false><<<grid, 256, 0, stream>>>(x, w, scale, bias, out);
    }
}

// Round 2
// 1099.602 us; speedup vs baseline: 1.2413x; 1.2413x over previous
//
#include <hip/hip_runtime.h>
#include <hip/hip_bf16.h>

#define M_TOT 16384
#define N_TOT 4096
#define K_TOT 4096

typedef __attribute__((ext_vector_type(8))) short bf16x8;
typedef __attribute__((ext_vector_type(4))) float f32x4;

typedef const __attribute__((address_space(1))) void* gptr_t;
typedef __attribute__((address_space(3))) void* lptr_t;

__device__ inline unsigned short f2bf(float f) {
    union { float f; unsigned u; } v; v.f = f;
    unsigned u = v.u;
    u += 0x7FFFu + ((u >> 16) & 1u);   // RNE
    return (unsigned short)(u >> 16);
}

__device__ inline unsigned short sgn_bf(float f) {
    union { float f; unsigned u; } v; v.f = f;
    // bf16 +-1.0 : sign | 0x3F80
    return (unsigned short)(((v.u >> 16) & 0x8000u) | 0x3F80u);
}

// ---------------------------------------------------------------------------
// Kernel 1: per-row scale = mean(|W|), binarize W -> bf16 +-1
// ---------------------------------------------------------------------------
__global__ void prep_weight(const float* __restrict__ w,
                            unsigned short* __restrict__ bw,  // may be null
                            float* __restrict__ scale) {
    const int row = blockIdx.x;
    const int tid = threadIdx.x;
    const float4* wr = (const float4*)(w + (size_t)row * K_TOT);
    float s = 0.f;
#pragma unroll
    for (int i = 0; i < 4; ++i) {
        int idx = tid + i * 256;            // float4 index 0..1023
        float4 v = wr[idx];
        s += fabsf(v.x) + fabsf(v.y) + fabsf(v.z) + fabsf(v.w);
        if (bw) {
            ushort4 b;
            b.x = sgn_bf(v.x); b.y = sgn_bf(v.y);
            b.z = sgn_bf(v.z); b.w = sgn_bf(v.w);
            *(ushort4*)(bw + (size_t)row * K_TOT + idx * 4) = b;
        }
    }
#pragma unroll
    for (int off = 32; off > 0; off >>= 1) s += __shfl_down(s, off, 64);
    __shared__ float red[4];
    if ((tid & 63) == 0) red[tid >> 6] = s;
    __syncthreads();
    if (tid == 0) scale[row] = (red[0] + red[1] + red[2] + red[3]) * (1.f / (float)K_TOT);
}

// ---------------------------------------------------------------------------
// Kernel 2: x fp32 -> bf16
// ---------------------------------------------------------------------------
__global__ void conv_x(const float* __restrict__ x, unsigned short* __restrict__ xb) {
    const long n4 = (long)M_TOT * K_TOT / 4;
    long i = (long)blockIdx.x * blockDim.x + threadIdx.x;
    const long stride = (long)gridDim.x * blockDim.x;
    for (; i < n4; i += stride) {
        float4 v = ((const float4*)x)[i];
        ushort4 b;
        b.x = f2bf(v.x); b.y = f2bf(v.y); b.z = f2bf(v.z); b.w = f2bf(v.w);
        ((ushort4*)xb)[i] = b;
    }
}

// ---------------------------------------------------------------------------
// Kernel 3 (fast path): m97-style GEMM with global_load_lds width=16 staging.
// 128x128 block tile, BK=32, 256 threads = 4 waves, wave does 64x64 (4x4 MFMA).
// LDS tiles UNPADDED [128][32] — required by global_load_lds lane ordering
// (wave-uniform base + lane*16B); m97/m98 measured this layout ~conflict-free.
// ---------------------------------------------------------------------------
__global__ __launch_bounds__(256) void gemm_bin_dma(const unsigned short* __restrict__ A,
                                                    const unsigned short* __restrict__ B,
                                                    const float* __restrict__ scale,
                                                    const float* __restrict__ bias,
                                                    float* __restrict__ out) {
    __shared__ unsigned short As[128 * 32];
    __shared__ unsigned short Bs[128 * 32];

    const int tid  = threadIdx.x;
    const int wave = tid >> 6;
    const int lane = tid & 63;
    const int quad = lane >> 4;
    const int l16  = lane & 15;
    const int wr   = wave >> 1;   // wave row (0..1)
    const int wc   = wave & 1;    // wave col (0..1)
    const int bn   = blockIdx.x * 128;
    const int bm   = blockIdx.y * 128;

    // per-lane source offsets for DMA staging: lane i covers row (i>>2), col (i&3)*8
    const int srow = lane >> 2;          // 0..15
    const int scol = (lane & 3) * 8;     // 0,8,16,24

    f32x4 acc[4][4] = {};

    for (int kt = 0; kt < K_TOT; kt += 32) {
        // each wave stages 2x16 rows of A and 2x16 rows of B (16B/lane DMA)
#pragma unroll
        for (int p = 0; p < 2; ++p) {
            const int rowbase = wave * 32 + p * 16;
            const unsigned short* ga =
                A + (size_t)(bm + rowbase + srow) * K_TOT + kt + scol;
            __builtin_amdgcn_global_load_lds((gptr_t)ga, (lptr_t)(As + rowbase * 32),
                                             16, 0, 0);
            const unsigned short* gb =
                B + (size_t)(bn + rowbase + srow) * K_TOT + kt + scol;
            __builtin_amdgcn_global_load_lds((gptr_t)gb, (lptr_t)(Bs + rowbase * 32),
                                             16, 0, 0);
        }
        __syncthreads();

        // A frag: A[m = l16][k = quad*8 + e];  B frag: W[n = l16][k = quad*8 + e]
        bf16x8 af[4], bfr[4];
#pragma unroll
        for (int i = 0; i < 4; ++i)
            af[i] = *(const bf16x8*)&As[(wr * 64 + i * 16 + l16) * 32 + quad * 8];
#pragma unroll
        for (int j = 0; j < 4; ++j)
            bfr[j] = *(const bf16x8*)&Bs[(wc * 64 + j * 16 + l16) * 32 + quad * 8];
#pragma unroll
        for (int i = 0; i < 4; ++i)
#pragma unroll
            for (int j = 0; j < 4; ++j)
                acc[i][j] = __builtin_amdgcn_mfma_f32_16x16x32_bf16(af[i], bfr[j], acc[i][j], 0, 0, 0);
        __syncthreads();
    }

    // epilogue: C/D layout col = l16, row = quad*4 + reg (verified m89/m91)
#pragma unroll
    for (int j = 0; j < 4; ++j) {
        const int gn = bn + wc * 64 + j * 16 + l16;
        const float sc = scale[gn];
        const float bi = bias[gn];
#pragma unroll
        for (int i = 0; i < 4; ++i) {
            const int gm0 = bm + wr * 64 + i * 16 + quad * 4;
#pragma unroll
            for (int r = 0; r < 4; ++r)
                out[(size_t)(gm0 + r) * N_TOT + gn] = acc[i][j][r] * sc + bi;
        }
    }
}

// ---------------------------------------------------------------------------
// Fallback (ws too small): fp32 inputs, inline convert, padded LDS
// ---------------------------------------------------------------------------
__global__ __launch_bounds__(256) void gemm_bin_fb(const float* __restrict__ A,
                                                   const float* __restrict__ Bf,
                                                   const float* __restrict__ scale,
                                                   const float* __restrict__ bias,
                                                   float* __restrict__ out) {
    __shared__ unsigned short As[128][40];
    __shared__ unsigned short Bs[128][40];

    const int tid  = threadIdx.x;
    const int wave = tid >> 6;
    const int lane = tid & 63;
    const int quad = lane >> 4;
    const int l16  = lane & 15;
    const int wr   = wave >> 1;
    const int wc   = wave & 1;
    const int bn   = blockIdx.x * 128;
    const int bm   = blockIdx.y * 128;

    f32x4 acc[4][4] = {};

    for (int kt = 0; kt < K_TOT; kt += 32) {
        const int row0 = tid >> 3;
        const int c4   = (tid & 7) * 4;
#pragma unroll
        for (int p = 0; p < 4; ++p) {
            int row = row0 + p * 32;
            float4 v = *(const float4*)(A + (size_t)(bm + row) * K_TOT + kt + c4);
            ushort4 b;
            b.x = f2bf(v.x); b.y = f2bf(v.y); b.z = f2bf(v.z); b.w = f2bf(v.w);
            *(ushort4*)&As[row][c4] = b;
        }
#pragma unroll
        for (int p = 0; p < 4; ++p) {
            int row = row0 + p * 32;
            float4 v = *(const float4*)(Bf + (size_t)(bn + row) * K_TOT + kt + c4);
            ushort4 b;
            b.x = sgn_bf(v.x); b.y = sgn_bf(v.y); b.z = sgn_bf(v.z); b.w = sgn_bf(v.w);
            *(ushort4*)&Bs[row][c4] = b;
        }
        __syncthreads();

        bf16x8 af[4], bfr[4];
#pragma unroll
        for (int i = 0; i < 4; ++i)
            af[i] = *(const bf16x8*)&As[wr * 64 + i * 16 + l16][quad * 8];
#pragma unroll
        for (int j = 0; j < 4; ++j)
            bfr[j] = *(const bf16x8*)&Bs[wc * 64 + j * 16 + l16][quad * 8];
#pragma unroll
        for (int i = 0; i < 4; ++i)
#pragma unroll
            for (int j = 0; j < 4; ++j)
                acc[i][j] = __builtin_amdgcn_mfma_f32_16x16x32_bf16(af[i], bfr[j], acc[i][j], 0, 0, 0);
        __syncthreads();
    }

#pragma unroll
    for (int j = 0; j < 4; ++j) {
        const int gn = bn + wc * 64 + j * 16 + l16;
        const float sc = scale[gn];
        const float bi = bias[gn];
#pragma unroll
        for (int i = 0; i < 4; ++i) {
            const int gm0 = bm + wr * 64 + i * 16 + quad * 4;
#pragma unroll
            for (int r = 0; r < 4; ++r)
                out[(size_t)(gm0 + r) * N_TOT + gn] = acc[i][j][r] * sc + bi;
        }
    }
}

// ---------------------------------------------------------------------------
extern "C" void kernel_launch(void* const* d_in, const int* in_sizes, int n_in,
                              void* d_out, int out_size, void* d_ws, size_t ws_size,
                              hipStream_t stream) {
    const float* x    = (const float*)d_in[0];
    const float* w    = (const float*)d_in[1];
    const float* bias = (const float*)d_in[2];
    float* out        = (float*)d_out;

    // ws layout: [scale 16KB][bw 32MB][xb 128MB]
    const size_t off_scale = 0;
    const size_t off_bw    = 16384;
    const size_t off_xb    = off_bw + (size_t)N_TOT * K_TOT * 2;
    const size_t need_full = off_xb + (size_t)M_TOT * K_TOT * 2;

    float* scale = (float*)((char*)d_ws + off_scale);
    const bool full = ws_size >= need_full;

    dim3 grid(N_TOT / 128, M_TOT / 128);

    if (full) {
        unsigned short* bw = (unsigned short*)((char*)d_ws + off_bw);
        unsigned short* xb = (unsigned short*)((char*)d_ws + off_xb);
        prep_weight<<<N_TOT, 256, 0, stream>>>(w, bw, scale);
        conv_x<<<8192, 256, 0, stream>>>(x, xb);
        gemm_bin_dma<<<grid, 256, 0, stream>>>(xb, bw, scale, bias, out);
    } else {
        prep_weight<<<N_TOT, 256, 0, stream>>>(w, nullptr, scale);
        gemm_bin_fb<<<grid, 256, 0, stream>>>(x, w, scale, bias, out);
    }
}